// Round 2
// 193.449 us; speedup vs baseline: 1.0619x; 1.0619x over previous
//
#include <hip/hip_runtime.h>
#include <math.h>

#define B_ 8
#define C_ 512
#define S_ 1024
#define HD 64
#define NHEADS 8
#define NGROUPS 8
#define DT_STEP 0.1f
#define EPS_GN 1e-5f
#define LOG2E 1.4426950408889634f

typedef __attribute__((ext_vector_type(8))) short bf16x8;
typedef __attribute__((ext_vector_type(4))) float f32x4;
typedef __attribute__((ext_vector_type(8))) unsigned short ushort8;
typedef __attribute__((ext_vector_type(4))) unsigned short ushort4_t;

static __device__ __forceinline__ unsigned short f2bf(float f) {     // RNE (cold paths)
  unsigned int u = __builtin_bit_cast(unsigned int, f);
  u += 0x7fff + ((u >> 16) & 1);
  return (unsigned short)(u >> 16);
}

static __device__ __forceinline__ unsigned short f2bf_fast(float f) { // round-half-up (hot paths)
  unsigned int u = __builtin_bit_cast(unsigned int, f);
  return (unsigned short)((u + 0x8000u) >> 16);
}

static __device__ __forceinline__ float bf2f(unsigned short u) {
  unsigned int t = ((unsigned int)u) << 16;
  return __builtin_bit_cast(float, t);
}

static __device__ __forceinline__ float exp2_raw(float x) {
  return __builtin_amdgcn_exp2f(x);    // single v_exp_f32
}

static __device__ __forceinline__ float fast_tanh(float x) {
  float xc = fminf(fmaxf(x, -15.f), 15.f);
  float e = exp2_raw(xc * (2.0f * LOG2E));
  return (e - 1.f) / (e + 1.f);
}

// ---------------- prep: cast fp32 weights -> bf16  +  GroupNorm partial sums ----------------
// qkv_w: row-major [o][c] bf16 (consumed by gemm_nt_core LDS staging)
// inl_w / proj_w: SLAB-INTERLEAVED layout W2[(c>>5)*16384 + o*32 + (c&31)]
//   -> each 32-k slab is a contiguous 32KB block [512 o][32 k]; the chain kernel's
//      B-fragment loads (16 o-rows x 64B) become fully-contiguous 1KB wave loads from L2.
__global__ __launch_bounds__(256) void prep_kernel(
    const float* __restrict__ a, const float* __restrict__ b, const float* __restrict__ c,
    unsigned short* __restrict__ A, unsigned short* __restrict__ B, unsigned short* __restrict__ C,
    const float* __restrict__ x, float* __restrict__ gpart) {
  int bid = blockIdx.x;
  int tid = threadIdx.x;
  if (bid < 384) {                     // qkv weights: plain row-major cast
    int off = bid * 2048;
    int i = off + tid * 8;
    f32x4 v0 = *(const f32x4*)(a + i);
    f32x4 v1 = *(const f32x4*)(a + i + 4);
    ushort8 o;
    o[0] = f2bf(v0[0]); o[1] = f2bf(v0[1]); o[2] = f2bf(v0[2]); o[3] = f2bf(v0[3]);
    o[4] = f2bf(v1[0]); o[5] = f2bf(v1[1]); o[6] = f2bf(v1[2]); o[7] = f2bf(v1[3]);
    *(ushort8*)(A + i) = o;
    return;
  }
  if (bid < 640) {                     // inl/proj weights: slab-interleaved cast
    const float* src; unsigned short* dst; int off;
    if (bid < 512) { src = b; dst = B; off = (bid - 384) * 2048; }
    else { src = c; dst = C; off = (bid - 512) * 2048; }
    int i = off + tid * 8;
    f32x4 v0 = *(const f32x4*)(src + i);
    f32x4 v1 = *(const f32x4*)(src + i + 4);
    ushort8 o;
    o[0] = f2bf(v0[0]); o[1] = f2bf(v0[1]); o[2] = f2bf(v0[2]); o[3] = f2bf(v0[3]);
    o[4] = f2bf(v1[0]); o[5] = f2bf(v1[1]); o[6] = f2bf(v1[2]); o[7] = f2bf(v1[3]);
    int orow = i >> 9, cbase = i & 511;
    int dsti = (cbase >> 5) * 16384 + orow * 32 + (cbase & 31);
    *(ushort8*)(dst + dsti) = o;
    return;
  }
  int sbid = bid - 640;
  int bg = sbid >> 3, chunk = sbid & 7;
  const float* xp = x + (size_t)bg * 65536 + (size_t)chunk * 8192;
  float sum = 0.f, sq = 0.f;
  #pragma unroll
  for (int i = 0; i < 8; ++i) {
    f32x4 v = *(const f32x4*)(xp + i * 1024 + tid * 4);
    sum += v[0] + v[1] + v[2] + v[3];
    sq += v[0]*v[0] + v[1]*v[1] + v[2]*v[2] + v[3]*v[3];
  }
  #pragma unroll
  for (int off = 32; off >= 1; off >>= 1) {
    sum += __shfl_xor(sum, off, 64);
    sq  += __shfl_xor(sq, off, 64);
  }
  __shared__ float s1[4], s2[4];
  int wave = tid >> 6, lane = tid & 63;
  if (lane == 0) { s1[wave] = sum; s2[wave] = sq; }
  __syncthreads();
  if (tid == 0) {
    float S = s1[0] + s1[1] + s1[2] + s1[3];
    float Q = s2[0] + s2[1] + s2[2] + s2[3];
    gpart[bg * 16 + chunk * 2] = S;
    gpart[bg * 16 + chunk * 2 + 1] = Q;
  }
}

// ---------------- GroupNorm pass 2: normalize + transpose to h_t[B,S,C] bf16 ----------------
__global__ __launch_bounds__(256) void gn_apply_t(
    const float* __restrict__ x, const float* __restrict__ gpart,
    const float* __restrict__ scale, const float* __restrict__ bias,
    unsigned short* __restrict__ h_t) {
  int bid = blockIdx.x;
  int bg = bid >> 4, st = bid & 15;
  int b = bg >> 3, g = bg & 7;
  float S = 0.f, Q = 0.f;
  #pragma unroll
  for (int i = 0; i < 8; ++i) {
    S += gpart[bg * 16 + i * 2];
    Q += gpart[bg * 16 + i * 2 + 1];
  }
  float mean = S / 65536.f;
  float var = Q / 65536.f - mean * mean;
  float inv = rsqrtf(var + EPS_GN);

  int tid = threadIdx.x;
  int sl = tid >> 2;
  int cq = (tid & 3) * 16;
  float sA[16], sB[16];
  #pragma unroll
  for (int u = 0; u < 16; ++u) {
    float scv = scale[g * 64 + cq + u];
    sA[u] = inv * scv;
    sB[u] = bias[g * 64 + cq + u] - mean * inv * scv;
  }

  const float* xp = x + ((size_t)b * C_ + (size_t)g * 64) * S_;
  __shared__ float tile[64][65];
  #pragma unroll
  for (int it = 0; it < 16; ++it) {
    int lin = it * 256 + tid;
    int c = lin >> 6, s = lin & 63;
    tile[c][s] = xp[(size_t)c * S_ + st * 64 + s];
  }
  __syncthreads();
  unsigned short vals[16];
  #pragma unroll
  for (int u = 0; u < 16; ++u)
    vals[u] = f2bf_fast(tile[cq + u][sl] * sA[u] + sB[u]);
  unsigned short* dst = h_t + ((size_t)b * S_ + st * 64 + sl) * C_ + g * 64 + cq;
  ushort8 lo, hi;
  #pragma unroll
  for (int u = 0; u < 8; ++u) { lo[u] = vals[u]; hi[u] = vals[u + 8]; }
  *(ushort8*)dst = lo;
  *(ushort8*)(dst + 8) = hi;
}

// ---------------- NT GEMM core, register-prefetch pipelined staging ----------------
// C[MB,NB] = A[MB,512] * B[NB,512]^T ; next k-slab loads issue during MFMA phase.
template<int MB, int NB, int WMG, int WNG>
__device__ __forceinline__ void gemm_nt_core(
    const unsigned short* __restrict__ Ab,
    const unsigned short* __restrict__ Bb,
    unsigned short* ldsA, unsigned short* ldsB,
    f32x4* acc) {
  constexpr int TI = (MB / WMG) / 16;
  constexpr int TJ = (NB / WNG) / 16;
  constexpr int NQA = MB * 4 / 256;          // 16B chunks per thread (A)
  constexpr int NQB = NB * 4 / 256;
  const int K = 512;
  const int tid = threadIdx.x;
  const int w = tid >> 6, lane = tid & 63, quad = lane >> 4, l15 = lane & 15;
  const int wm = (WNG == 1) ? w : ((WMG == 1) ? 0 : (w >> 1));
  const int wn = (WNG == 1) ? 0 : ((WMG == 1) ? w : (w & 1));

  ushort8 apf[NQA], bpf[NQB];
  #pragma unroll
  for (int q = 0; q < NQA; ++q) {
    int c = q * 256 + tid;
    apf[q] = *(const ushort8*)(Ab + (size_t)(c >> 2) * K + (c & 3) * 8);
  }
  #pragma unroll
  for (int q = 0; q < NQB; ++q) {
    int c = q * 256 + tid;
    bpf[q] = *(const ushort8*)(Bb + (size_t)(c >> 2) * K + (c & 3) * 8);
  }

  for (int k0 = 0; k0 < K; k0 += 32) {
    __syncthreads();                         // prior slab consumed
    #pragma unroll
    for (int q = 0; q < NQA; ++q) {
      int c = q * 256 + tid;
      *(ushort8*)(ldsA + c * 8) = apf[q];
    }
    #pragma unroll
    for (int q = 0; q < NQB; ++q) {
      int c = q * 256 + tid;
      *(ushort8*)(ldsB + c * 8) = bpf[q];
    }
    __syncthreads();
    if (k0 + 32 < K) {                       // issue next-slab loads; waited next iter
      #pragma unroll
      for (int q = 0; q < NQA; ++q) {
        int c = q * 256 + tid;
        apf[q] = *(const ushort8*)(Ab + (size_t)(c >> 2) * K + k0 + 32 + (c & 3) * 8);
      }
      #pragma unroll
      for (int q = 0; q < NQB; ++q) {
        int c = q * 256 + tid;
        bpf[q] = *(const ushort8*)(Bb + (size_t)(c >> 2) * K + k0 + 32 + (c & 3) * 8);
      }
    }
    bf16x8 af[TI], bfr[TJ];
    #pragma unroll
    for (int i = 0; i < TI; ++i)
      af[i] = *(const bf16x8*)(ldsA + (wm * (MB / WMG) + i * 16 + l15) * 32 + quad * 8);
    #pragma unroll
    for (int j = 0; j < TJ; ++j)
      bfr[j] = *(const bf16x8*)(ldsB + (wn * (NB / WNG) + j * 16 + l15) * 32 + quad * 8);
    #pragma unroll
    for (int i = 0; i < TI; ++i)
      #pragma unroll
      for (int j = 0; j < TJ; ++j)
        acc[i * TJ + j] = __builtin_amdgcn_mfma_f32_16x16x32_bf16(af[i], bfr[j], acc[i * TJ + j], 0, 0, 0);
  }
}

// ---------------- QKV GEMM: W_bf[1536,512] x h_t[b][1024,512]^T ----------------
__global__ __launch_bounds__(256) void gemm_qkv_mfma(
    const unsigned short* __restrict__ Wbf, const unsigned short* __restrict__ h_t,
    const float* __restrict__ bias,
    unsigned short* __restrict__ Qt, unsigned short* __restrict__ Kt,
    unsigned short* __restrict__ Vt) {
  __shared__ __align__(16) unsigned short ldsA[128 * 32];
  __shared__ __align__(16) unsigned short ldsB[128 * 32];
  int b = blockIdx.z;
  int bm = blockIdx.y * 128, bn = blockIdx.x * 128;
  f32x4 acc[16];
  #pragma unroll
  for (int t = 0; t < 16; ++t) acc[t] = (f32x4){0.f, 0.f, 0.f, 0.f};
  gemm_nt_core<128, 128, 2, 2>(Wbf + (size_t)bm * 512,
                               h_t + ((size_t)b * S_ + bn) * 512, ldsA, ldsB, acc);
  int tid = threadIdx.x, w = tid >> 6, lane = tid & 63, quad = lane >> 4, l15 = lane & 15;
  int wm = w >> 1, wn = w & 1;
  int tensor = bm >> 9;
  float qscale = (tensor == 0) ? 0.125f * LOG2E : 1.0f;
  #pragma unroll
  for (int i = 0; i < 4; ++i) {
    #pragma unroll
    for (int j = 0; j < 4; ++j) {
      int m0 = bm + wm * 64 + i * 16 + quad * 4;
      int ng = bn + wn * 64 + j * 16 + l15;
      f32x4 v = acc[i * 4 + j];
      if (tensor < 2) {
        int head = (m0 >> 6) & 7, d0 = m0 & 63;
        ushort4_t pk;
        #pragma unroll
        for (int r = 0; r < 4; ++r) pk[r] = f2bf((v[r] + bias[m0 + r]) * qscale);
        unsigned short* dst = (tensor ? Kt : Qt) +
            (((size_t)(b * 8 + head) * S_ + ng) * 64 + d0);
        *(ushort4_t*)dst = pk;
      } else {
        #pragma unroll
        for (int r = 0; r < 4; ++r)
          Vt[(size_t)b * (C_ * S_) + (size_t)(m0 - 1024 + r) * S_ + ng] = f2bf(v[r] + bias[m0 + r]);
      }
    }
  }
}

// ---------------- Flash attention: transposed scores, 2 q-groups/wave, reg-prefetched K/V ----------------
// grid 512: bid = sblk*64 + (b*8+n); 4 waves x 32 q-rows (2 groups of 16)
__global__ __launch_bounds__(256) void attn_mfma(
    const unsigned short* __restrict__ Qt,   // [B][NH][S][HD] (pre-scaled, incl log2e)
    const unsigned short* __restrict__ Kt,
    const unsigned short* __restrict__ Vt,   // [B][C][S]
    unsigned short* __restrict__ hflat_bf) { // [B][S][C] bf16
  int tid = threadIdx.x, wave = tid >> 6, lane = tid & 63;
  int quad = lane >> 4, l15 = lane & 15;
  int bid = blockIdx.x;
  int bn = bid & 63, sblk = bid >> 6, b = bn >> 3, n = bn & 7;
  int s0w = sblk * 128 + wave * 32;

  __shared__ unsigned short k_lds[64][72];
  __shared__ unsigned short v_lds[64][72];
  __shared__ unsigned short p_lds[4][2][16][72];  // [wave][group][s][t], A-layout

  const unsigned short* Kb = Kt + ((size_t)(b * 8 + n)) * S_ * 64;
  const unsigned short* Vb = Vt + ((size_t)b * C_ + n * 64) * S_;

  bf16x8 qa[2][2];
  #pragma unroll
  for (int g = 0; g < 2; ++g) {
    const unsigned short* Qb = Qt + (((size_t)(b * 8 + n)) * S_ + s0w + g * 16 + l15) * 64;
    qa[g][0] = *(const bf16x8*)(Qb + quad * 8);
    qa[g][1] = *(const bf16x8*)(Qb + 32 + quad * 8);
  }

  bf16x8 ones;
  #pragma unroll
  for (int j = 0; j < 8; ++j) ones[j] = (short)0x3F80;

  f32x4 o_acc[2][4];
  f32x4 l_acc[2];
  #pragma unroll
  for (int g = 0; g < 2; ++g) {
    l_acc[g] = (f32x4){0.f, 0.f, 0.f, 0.f};
    #pragma unroll
    for (int dc = 0; dc < 4; ++dc) o_acc[g][dc] = (f32x4){0.f, 0.f, 0.f, 0.f};
  }

  int row0 = tid >> 3, c80 = (tid & 7) * 8;
  int row1 = (tid + 256) >> 3, c81 = c80;

  ushort8 kreg[2], vreg[2];
  kreg[0] = *(const ushort8*)(Kb + (size_t)row0 * 64 + c80);
  kreg[1] = *(const ushort8*)(Kb + (size_t)row1 * 64 + c81);
  vreg[0] = *(const ushort8*)(Vb + (size_t)row0 * S_ + c80);
  vreg[1] = *(const ushort8*)(Vb + (size_t)row1 * S_ + c81);

  for (int t0 = 0; t0 < S_; t0 += 64) {
    __syncthreads();
    *(ushort8*)&k_lds[row0][c80] = kreg[0];
    *(ushort8*)&k_lds[row1][c81] = kreg[1];
    *(ushort8*)&v_lds[row0][c80] = vreg[0];
    *(ushort8*)&v_lds[row1][c81] = vreg[1];
    __syncthreads();
    if (t0 + 64 < S_) {
      int t1 = t0 + 64;
      kreg[0] = *(const ushort8*)(Kb + (size_t)(t1 + row0) * 64 + c80);
      kreg[1] = *(const ushort8*)(Kb + (size_t)(t1 + row1) * 64 + c81);
      vreg[0] = *(const ushort8*)(Vb + (size_t)row0 * S_ + t1 + c80);
      vreg[1] = *(const ushort8*)(Vb + (size_t)row1 * S_ + t1 + c81);
    }

    // Transposed scores: St[t][s] = sum_d K[t][d] Q[s][d]
    f32x4 sc[2][4];
    #pragma unroll
    for (int tc = 0; tc < 4; ++tc) {
      bf16x8 kb0 = *(const bf16x8*)&k_lds[tc * 16 + l15][quad * 8];
      bf16x8 kb1 = *(const bf16x8*)&k_lds[tc * 16 + l15][32 + quad * 8];
      #pragma unroll
      for (int g = 0; g < 2; ++g) {
        f32x4 c = {0.f, 0.f, 0.f, 0.f};
        c = __builtin_amdgcn_mfma_f32_16x16x32_bf16(kb0, qa[g][0], c, 0, 0, 0);
        sc[g][tc] = __builtin_amdgcn_mfma_f32_16x16x32_bf16(kb1, qa[g][1], c, 0, 0, 0);
      }
    }

    // exp -> P[s][t] in LDS via contiguous b64 writes
    #pragma unroll
    for (int g = 0; g < 2; ++g)
      #pragma unroll
      for (int tc = 0; tc < 4; ++tc) {
        ushort4_t p4;
        #pragma unroll
        for (int r = 0; r < 4; ++r) p4[r] = f2bf_fast(exp2_raw(sc[g][tc][r]));
        *(ushort4_t*)&p_lds[wave][g][l15][tc * 16 + quad * 4] = p4;
      }

    bf16x8 pa[2][2];
    #pragma unroll
    for (int g = 0; g < 2; ++g) {
      pa[g][0] = *(const bf16x8*)&p_lds[wave][g][l15][quad * 8];
      pa[g][1] = *(const bf16x8*)&p_lds[wave][g][l15][32 + quad * 8];
      l_acc[g] = __builtin_amdgcn_mfma_f32_16x16x32_bf16(pa[g][0], ones, l_acc[g], 0, 0, 0);
      l_acc[g] = __builtin_amdgcn_mfma_f32_16x16x32_bf16(pa[g][1], ones, l_acc[g], 0, 0, 0);
    }
    #pragma unroll
    for (int dc = 0; dc < 4; ++dc) {
      bf16x8 vb0 = *(const bf16x8*)&v_lds[dc * 16 + l15][quad * 8];
      bf16x8 vb1 = *(const bf16x8*)&v_lds[dc * 16 + l15][32 + quad * 8];
      #pragma unroll
      for (int g = 0; g < 2; ++g) {
        o_acc[g][dc] = __builtin_amdgcn_mfma_f32_16x16x32_bf16(pa[g][0], vb0, o_acc[g][dc], 0, 0, 0);
        o_acc[g][dc] = __builtin_amdgcn_mfma_f32_16x16x32_bf16(pa[g][1], vb1, o_acc[g][dc], 0, 0, 0);
      }
    }
  }

  #pragma unroll
  for (int g = 0; g < 2; ++g) {
    float inv_l[4];
    #pragma unroll
    for (int r = 0; r < 4; ++r) inv_l[r] = 1.f / l_acc[g][r];
    #pragma unroll
    for (int dc = 0; dc < 4; ++dc) {
      #pragma unroll
      for (int r = 0; r < 4; ++r) {
        int s = s0w + g * 16 + quad * 4 + r;
        size_t idx = ((size_t)b * S_ + s) * C_ + n * 64 + dc * 16 + l15;
        hflat_bf[idx] = f2bf_fast(o_acc[g][dc][r] * inv_l[r]);
      }
    }
  }
}

// ---------------- Fused INL x3 + proj + residual: h rows resident in LDS ----------------
// 256 blocks (1/CU) x 512 threads (8 waves). Block owns 32 rows of h [32][512] bf16 in LDS.
// W consumed straight from L2 via slab-interleaved layout: each B-frag load = 1KB contiguous.
// No barriers inside the K-loop; 2 barriers per INL step around the in-LDS tanh update.
__global__ __launch_bounds__(512) void inl_proj_chain(
    const unsigned short* __restrict__ hbf,   // [B*S][512] bf16 (attn out rows)
    const unsigned short* __restrict__ Wi2,   // inl W, slab-interleaved [16][512][32]
    const unsigned short* __restrict__ Wp2,   // proj W, slab-interleaved
    const float* __restrict__ ib, const float* __restrict__ pb,
    const float* __restrict__ x, float* __restrict__ Out) {
  __shared__ __align__(16) unsigned short h_lds[32][520];   // pad 520: 2-way max on b128 frag reads

  int tid = threadIdx.x;
  int wave = tid >> 6, lane = tid & 63, quad = lane >> 4, l15 = lane & 15;
  int wo = wave * 64;                        // this wave's 64 output channels
  int bid = blockIdx.x;
  int b = bid >> 5, s0 = (bid & 31) * 32;    // 32 blocks per batch image

  // stage this block's 32 h rows (32KB), coalesced 16B/lane
  const unsigned short* hsrc = hbf + (size_t)bid * 16384;
  #pragma unroll
  for (int it = 0; it < 4; ++it) {
    int lin = it * 512 + tid;
    ushort8 v = *(const ushort8*)(hsrc + (size_t)lin * 8);
    *(ushort8*)&h_lds[lin >> 6][(lin & 63) * 8] = v;
  }

  float bias_i[4], bias_p[4];
  #pragma unroll
  for (int j = 0; j < 4; ++j) {
    bias_i[j] = ib[wo + j * 16 + l15];
    bias_p[j] = pb[wo + j * 16 + l15];
  }

  f32x4 acc[2][4];
  #pragma unroll
  for (int i = 0; i < 2; ++i)
    #pragma unroll
    for (int j = 0; j < 4; ++j) acc[i][j] = (f32x4){0.f, 0.f, 0.f, 0.f};

  __syncthreads();                           // h_lds ready

  for (int step = 0; step < 4; ++step) {
    const unsigned short* Wb = (step < 3) ? Wi2 : Wp2;
    #pragma unroll 4
    for (int slab = 0; slab < 16; ++slab) {
      const unsigned short* wp = Wb + slab * 16384;
      bf16x8 afr[2], bfr[4];
      #pragma unroll
      for (int i = 0; i < 2; ++i)
        afr[i] = *(const bf16x8*)&h_lds[i * 16 + l15][slab * 32 + quad * 8];
      #pragma unroll
      for (int j = 0; j < 4; ++j)
        bfr[j] = *(const bf16x8*)(wp + (size_t)(wo + j * 16 + l15) * 32 + quad * 8);
      #pragma unroll
      for (int i = 0; i < 2; ++i)
        #pragma unroll
        for (int j = 0; j < 4; ++j)
          acc[i][j] = __builtin_amdgcn_mfma_f32_16x16x32_bf16(afr[i], bfr[j], acc[i][j], 0, 0, 0);
    }
    if (step < 3) {
      __syncthreads();                       // all waves done reading h this step
      #pragma unroll
      for (int i = 0; i < 2; ++i)
        #pragma unroll
        for (int j = 0; j < 4; ++j) {
          int o = wo + j * 16 + l15;
          #pragma unroll
          for (int r = 0; r < 4; ++r) {
            int s = i * 16 + quad * 4 + r;
            float hv = bf2f(h_lds[s][o]);
            h_lds[s][o] = f2bf_fast(hv + DT_STEP * fast_tanh(acc[i][j][r] + bias_i[j]));
            acc[i][j][r] = 0.f;
          }
        }
      __syncthreads();                       // updates visible before next step's reads
    }
  }

  // proj epilogue: Out[b][o][s0..] = x + pb + acc ; 4 consecutive s per reg quad -> f32x4
  #pragma unroll
  for (int i = 0; i < 2; ++i)
    #pragma unroll
    for (int j = 0; j < 4; ++j) {
      int o = wo + j * 16 + l15;
      size_t base = (((size_t)b * 512 + o) << 10) + (size_t)(s0 + i * 16 + quad * 4);
      f32x4 xv = *(const f32x4*)(x + base);
      f32x4 ov;
      #pragma unroll
      for (int r = 0; r < 4; ++r) ov[r] = xv[r] + bias_p[j] + acc[i][j][r];
      *(f32x4*)(Out + base) = ov;
    }
}

extern "C" void kernel_launch(void* const* d_in, const int* in_sizes, int n_in,
                              void* d_out, int out_size, void* d_ws, size_t ws_size,
                              hipStream_t stream) {
  const float* x        = (const float*)d_in[0];
  const float* gn_scale = (const float*)d_in[1];
  const float* gn_bias  = (const float*)d_in[2];
  const float* qkv_w    = (const float*)d_in[3];
  const float* qkv_b    = (const float*)d_in[4];
  const float* proj_w   = (const float*)d_in[5];
  const float* proj_b   = (const float*)d_in[6];
  const float* inl_w    = (const float*)d_in[7];
  const float* inl_b    = (const float*)d_in[8];
  float* out = (float*)d_out;
  float* ws = (float*)d_ws;

  unsigned short* Qt  = (unsigned short*)(ws + 8388608);
  unsigned short* Kt  = (unsigned short*)(ws + 10485760);
  unsigned short* Vt  = (unsigned short*)(ws + 12582912);
  unsigned short* h_t = (unsigned short*)(ws + 14680064);
  unsigned short* Abf = (unsigned short*)(ws + 16777216);
  float* gpart = ws + 18874368;
  unsigned short* qkvw_bf  = (unsigned short*)(ws + 18878464);
  unsigned short* inlw_bf  = qkvw_bf + 786432;
  unsigned short* projw_bf = inlw_bf + 262144;

  prep_kernel<<<1152, 256, 0, stream>>>(qkv_w, inl_w, proj_w, qkvw_bf, inlw_bf, projw_bf, x, gpart);
  gn_apply_t<<<1024, 256, 0, stream>>>(x, gpart, gn_scale, gn_bias, h_t);
  gemm_qkv_mfma<<<dim3(8, 12, 8), 256, 0, stream>>>(qkvw_bf, h_t, qkv_b, Qt, Kt, Vt);
  attn_mfma<<<512, 256, 0, stream>>>(Qt, Kt, Vt, Abf);
  inl_proj_chain<<<256, 512, 0, stream>>>(Abf, inlw_bf, projw_bf, inl_b, proj_b, x, out);
}

// Round 3
// 189.417 us; speedup vs baseline: 1.0845x; 1.0213x over previous
//
#include <hip/hip_runtime.h>
#include <math.h>

#define B_ 8
#define C_ 512
#define S_ 1024
#define HD 64
#define NHEADS 8
#define NGROUPS 8
#define DT_STEP 0.1f
#define EPS_GN 1e-5f
#define LOG2E 1.4426950408889634f

typedef __attribute__((ext_vector_type(8))) short bf16x8;
typedef __attribute__((ext_vector_type(4))) float f32x4;
typedef __attribute__((ext_vector_type(8))) unsigned short ushort8;
typedef __attribute__((ext_vector_type(4))) unsigned short ushort4_t;

static __device__ __forceinline__ unsigned short f2bf(float f) {     // RNE (cold paths)
  unsigned int u = __builtin_bit_cast(unsigned int, f);
  u += 0x7fff + ((u >> 16) & 1);
  return (unsigned short)(u >> 16);
}

static __device__ __forceinline__ unsigned short f2bf_fast(float f) { // round-half-up (hot paths)
  unsigned int u = __builtin_bit_cast(unsigned int, f);
  return (unsigned short)((u + 0x8000u) >> 16);
}

static __device__ __forceinline__ float bf2f(unsigned short u) {
  unsigned int t = ((unsigned int)u) << 16;
  return __builtin_bit_cast(float, t);
}

static __device__ __forceinline__ float exp2_raw(float x) {
  return __builtin_amdgcn_exp2f(x);    // single v_exp_f32
}

static __device__ __forceinline__ float fast_tanh(float x) {
  float xc = fminf(fmaxf(x, -15.f), 15.f);
  float e = exp2_raw(xc * (2.0f * LOG2E));
  return (e - 1.f) / (e + 1.f);
}

// ---------------- prep: cast fp32 weights -> bf16  +  GroupNorm partial sums ----------------
// qkv_w: row-major [o][c] bf16 (consumed by gemm_nt_core LDS staging)
// inl_w / proj_w: SLAB-INTERLEAVED layout W2[(c>>5)*16384 + o*32 + (c&31)]
//   -> each 32-k slab is a contiguous 32KB block [512 o][32 k]; the chain kernel's
//      B-fragment loads (16 o-rows x 64B) become fully-contiguous 1KB wave loads from L2.
__global__ __launch_bounds__(256) void prep_kernel(
    const float* __restrict__ a, const float* __restrict__ b, const float* __restrict__ c,
    unsigned short* __restrict__ A, unsigned short* __restrict__ B, unsigned short* __restrict__ C,
    const float* __restrict__ x, float* __restrict__ gpart) {
  int bid = blockIdx.x;
  int tid = threadIdx.x;
  if (bid < 384) {                     // qkv weights: plain row-major cast
    int off = bid * 2048;
    int i = off + tid * 8;
    f32x4 v0 = *(const f32x4*)(a + i);
    f32x4 v1 = *(const f32x4*)(a + i + 4);
    ushort8 o;
    o[0] = f2bf(v0[0]); o[1] = f2bf(v0[1]); o[2] = f2bf(v0[2]); o[3] = f2bf(v0[3]);
    o[4] = f2bf(v1[0]); o[5] = f2bf(v1[1]); o[6] = f2bf(v1[2]); o[7] = f2bf(v1[3]);
    *(ushort8*)(A + i) = o;
    return;
  }
  if (bid < 640) {                     // inl/proj weights: slab-interleaved cast
    const float* src; unsigned short* dst; int off;
    if (bid < 512) { src = b; dst = B; off = (bid - 384) * 2048; }
    else { src = c; dst = C; off = (bid - 512) * 2048; }
    int i = off + tid * 8;
    f32x4 v0 = *(const f32x4*)(src + i);
    f32x4 v1 = *(const f32x4*)(src + i + 4);
    ushort8 o;
    o[0] = f2bf(v0[0]); o[1] = f2bf(v0[1]); o[2] = f2bf(v0[2]); o[3] = f2bf(v0[3]);
    o[4] = f2bf(v1[0]); o[5] = f2bf(v1[1]); o[6] = f2bf(v1[2]); o[7] = f2bf(v1[3]);
    int orow = i >> 9, cbase = i & 511;
    int dsti = (cbase >> 5) * 16384 + orow * 32 + (cbase & 31);
    *(ushort8*)(dst + dsti) = o;
    return;
  }
  int sbid = bid - 640;
  int bg = sbid >> 3, chunk = sbid & 7;
  const float* xp = x + (size_t)bg * 65536 + (size_t)chunk * 8192;
  float sum = 0.f, sq = 0.f;
  #pragma unroll
  for (int i = 0; i < 8; ++i) {
    f32x4 v = *(const f32x4*)(xp + i * 1024 + tid * 4);
    sum += v[0] + v[1] + v[2] + v[3];
    sq += v[0]*v[0] + v[1]*v[1] + v[2]*v[2] + v[3]*v[3];
  }
  #pragma unroll
  for (int off = 32; off >= 1; off >>= 1) {
    sum += __shfl_xor(sum, off, 64);
    sq  += __shfl_xor(sq, off, 64);
  }
  __shared__ float s1[4], s2[4];
  int wave = tid >> 6, lane = tid & 63;
  if (lane == 0) { s1[wave] = sum; s2[wave] = sq; }
  __syncthreads();
  if (tid == 0) {
    float S = s1[0] + s1[1] + s1[2] + s1[3];
    float Q = s2[0] + s2[1] + s2[2] + s2[3];
    gpart[bg * 16 + chunk * 2] = S;
    gpart[bg * 16 + chunk * 2 + 1] = Q;
  }
}

// ---------------- GroupNorm pass 2: normalize + transpose to h_t[B,S,C] bf16 ----------------
__global__ __launch_bounds__(256) void gn_apply_t(
    const float* __restrict__ x, const float* __restrict__ gpart,
    const float* __restrict__ scale, const float* __restrict__ bias,
    unsigned short* __restrict__ h_t) {
  int bid = blockIdx.x;
  int bg = bid >> 4, st = bid & 15;
  int b = bg >> 3, g = bg & 7;
  float S = 0.f, Q = 0.f;
  #pragma unroll
  for (int i = 0; i < 8; ++i) {
    S += gpart[bg * 16 + i * 2];
    Q += gpart[bg * 16 + i * 2 + 1];
  }
  float mean = S / 65536.f;
  float var = Q / 65536.f - mean * mean;
  float inv = rsqrtf(var + EPS_GN);

  int tid = threadIdx.x;
  int sl = tid >> 2;
  int cq = (tid & 3) * 16;
  float sA[16], sB[16];
  #pragma unroll
  for (int u = 0; u < 16; ++u) {
    float scv = scale[g * 64 + cq + u];
    sA[u] = inv * scv;
    sB[u] = bias[g * 64 + cq + u] - mean * inv * scv;
  }

  const float* xp = x + ((size_t)b * C_ + (size_t)g * 64) * S_;
  __shared__ float tile[64][65];
  #pragma unroll
  for (int it = 0; it < 16; ++it) {
    int lin = it * 256 + tid;
    int c = lin >> 6, s = lin & 63;
    tile[c][s] = xp[(size_t)c * S_ + st * 64 + s];
  }
  __syncthreads();
  unsigned short vals[16];
  #pragma unroll
  for (int u = 0; u < 16; ++u)
    vals[u] = f2bf_fast(tile[cq + u][sl] * sA[u] + sB[u]);
  unsigned short* dst = h_t + ((size_t)b * S_ + st * 64 + sl) * C_ + g * 64 + cq;
  ushort8 lo, hi;
  #pragma unroll
  for (int u = 0; u < 8; ++u) { lo[u] = vals[u]; hi[u] = vals[u + 8]; }
  *(ushort8*)dst = lo;
  *(ushort8*)(dst + 8) = hi;
}

// ---------------- NT GEMM core, register-prefetch pipelined staging ----------------
// C[MB,NB] = A[MB,512] * B[NB,512]^T ; next k-slab loads issue during MFMA phase.
template<int MB, int NB, int WMG, int WNG>
__device__ __forceinline__ void gemm_nt_core(
    const unsigned short* __restrict__ Ab,
    const unsigned short* __restrict__ Bb,
    unsigned short* ldsA, unsigned short* ldsB,
    f32x4* acc) {
  constexpr int TI = (MB / WMG) / 16;
  constexpr int TJ = (NB / WNG) / 16;
  constexpr int NQA = MB * 4 / 256;          // 16B chunks per thread (A)
  constexpr int NQB = NB * 4 / 256;
  const int K = 512;
  const int tid = threadIdx.x;
  const int w = tid >> 6, lane = tid & 63, quad = lane >> 4, l15 = lane & 15;
  const int wm = (WNG == 1) ? w : ((WMG == 1) ? 0 : (w >> 1));
  const int wn = (WNG == 1) ? 0 : ((WMG == 1) ? w : (w & 1));

  ushort8 apf[NQA], bpf[NQB];
  #pragma unroll
  for (int q = 0; q < NQA; ++q) {
    int c = q * 256 + tid;
    apf[q] = *(const ushort8*)(Ab + (size_t)(c >> 2) * K + (c & 3) * 8);
  }
  #pragma unroll
  for (int q = 0; q < NQB; ++q) {
    int c = q * 256 + tid;
    bpf[q] = *(const ushort8*)(Bb + (size_t)(c >> 2) * K + (c & 3) * 8);
  }

  for (int k0 = 0; k0 < K; k0 += 32) {
    __syncthreads();                         // prior slab consumed
    #pragma unroll
    for (int q = 0; q < NQA; ++q) {
      int c = q * 256 + tid;
      *(ushort8*)(ldsA + c * 8) = apf[q];
    }
    #pragma unroll
    for (int q = 0; q < NQB; ++q) {
      int c = q * 256 + tid;
      *(ushort8*)(ldsB + c * 8) = bpf[q];
    }
    __syncthreads();
    if (k0 + 32 < K) {                       // issue next-slab loads; waited next iter
      #pragma unroll
      for (int q = 0; q < NQA; ++q) {
        int c = q * 256 + tid;
        apf[q] = *(const ushort8*)(Ab + (size_t)(c >> 2) * K + k0 + 32 + (c & 3) * 8);
      }
      #pragma unroll
      for (int q = 0; q < NQB; ++q) {
        int c = q * 256 + tid;
        bpf[q] = *(const ushort8*)(Bb + (size_t)(c >> 2) * K + k0 + 32 + (c & 3) * 8);
      }
    }
    bf16x8 af[TI], bfr[TJ];
    #pragma unroll
    for (int i = 0; i < TI; ++i)
      af[i] = *(const bf16x8*)(ldsA + (wm * (MB / WMG) + i * 16 + l15) * 32 + quad * 8);
    #pragma unroll
    for (int j = 0; j < TJ; ++j)
      bfr[j] = *(const bf16x8*)(ldsB + (wn * (NB / WNG) + j * 16 + l15) * 32 + quad * 8);
    #pragma unroll
    for (int i = 0; i < TI; ++i)
      #pragma unroll
      for (int j = 0; j < TJ; ++j)
        acc[i * TJ + j] = __builtin_amdgcn_mfma_f32_16x16x32_bf16(af[i], bfr[j], acc[i * TJ + j], 0, 0, 0);
  }
}

// ---------------- QKV GEMM: W_bf[1536,512] x h_t[b][1024,512]^T ----------------
__global__ __launch_bounds__(256) void gemm_qkv_mfma(
    const unsigned short* __restrict__ Wbf, const unsigned short* __restrict__ h_t,
    const float* __restrict__ bias,
    unsigned short* __restrict__ Qt, unsigned short* __restrict__ Kt,
    unsigned short* __restrict__ Vt) {
  __shared__ __align__(16) unsigned short ldsA[128 * 32];
  __shared__ __align__(16) unsigned short ldsB[128 * 32];
  int b = blockIdx.z;
  int bm = blockIdx.y * 128, bn = blockIdx.x * 128;
  f32x4 acc[16];
  #pragma unroll
  for (int t = 0; t < 16; ++t) acc[t] = (f32x4){0.f, 0.f, 0.f, 0.f};
  gemm_nt_core<128, 128, 2, 2>(Wbf + (size_t)bm * 512,
                               h_t + ((size_t)b * S_ + bn) * 512, ldsA, ldsB, acc);
  int tid = threadIdx.x, w = tid >> 6, lane = tid & 63, quad = lane >> 4, l15 = lane & 15;
  int wm = w >> 1, wn = w & 1;
  int tensor = bm >> 9;
  float qscale = (tensor == 0) ? 0.125f * LOG2E : 1.0f;
  #pragma unroll
  for (int i = 0; i < 4; ++i) {
    #pragma unroll
    for (int j = 0; j < 4; ++j) {
      int m0 = bm + wm * 64 + i * 16 + quad * 4;
      int ng = bn + wn * 64 + j * 16 + l15;
      f32x4 v = acc[i * 4 + j];
      if (tensor < 2) {
        int head = (m0 >> 6) & 7, d0 = m0 & 63;
        ushort4_t pk;
        #pragma unroll
        for (int r = 0; r < 4; ++r) pk[r] = f2bf((v[r] + bias[m0 + r]) * qscale);
        unsigned short* dst = (tensor ? Kt : Qt) +
            (((size_t)(b * 8 + head) * S_ + ng) * 64 + d0);
        *(ushort4_t*)dst = pk;
      } else {
        #pragma unroll
        for (int r = 0; r < 4; ++r)
          Vt[(size_t)b * (C_ * S_) + (size_t)(m0 - 1024 + r) * S_ + ng] = f2bf(v[r] + bias[m0 + r]);
      }
    }
  }
}

// ---------------- Flash attention: transposed scores, 2 q-groups/wave, reg-prefetched K/V ----------------
// grid 512: bid = sblk*64 + (b*8+n); 4 waves x 32 q-rows (2 groups of 16)
__global__ __launch_bounds__(256) void attn_mfma(
    const unsigned short* __restrict__ Qt,   // [B][NH][S][HD] (pre-scaled, incl log2e)
    const unsigned short* __restrict__ Kt,
    const unsigned short* __restrict__ Vt,   // [B][C][S]
    unsigned short* __restrict__ hflat_bf) { // [B][S][C] bf16
  int tid = threadIdx.x, wave = tid >> 6, lane = tid & 63;
  int quad = lane >> 4, l15 = lane & 15;
  int bid = blockIdx.x;
  int bn = bid & 63, sblk = bid >> 6, b = bn >> 3, n = bn & 7;
  int s0w = sblk * 128 + wave * 32;

  __shared__ unsigned short k_lds[64][72];
  __shared__ unsigned short v_lds[64][72];
  __shared__ unsigned short p_lds[4][2][16][72];  // [wave][group][s][t], A-layout

  const unsigned short* Kb = Kt + ((size_t)(b * 8 + n)) * S_ * 64;
  const unsigned short* Vb = Vt + ((size_t)b * C_ + n * 64) * S_;

  bf16x8 qa[2][2];
  #pragma unroll
  for (int g = 0; g < 2; ++g) {
    const unsigned short* Qb = Qt + (((size_t)(b * 8 + n)) * S_ + s0w + g * 16 + l15) * 64;
    qa[g][0] = *(const bf16x8*)(Qb + quad * 8);
    qa[g][1] = *(const bf16x8*)(Qb + 32 + quad * 8);
  }

  bf16x8 ones;
  #pragma unroll
  for (int j = 0; j < 8; ++j) ones[j] = (short)0x3F80;

  f32x4 o_acc[2][4];
  f32x4 l_acc[2];
  #pragma unroll
  for (int g = 0; g < 2; ++g) {
    l_acc[g] = (f32x4){0.f, 0.f, 0.f, 0.f};
    #pragma unroll
    for (int dc = 0; dc < 4; ++dc) o_acc[g][dc] = (f32x4){0.f, 0.f, 0.f, 0.f};
  }

  int row0 = tid >> 3, c80 = (tid & 7) * 8;
  int row1 = (tid + 256) >> 3, c81 = c80;

  ushort8 kreg[2], vreg[2];
  kreg[0] = *(const ushort8*)(Kb + (size_t)row0 * 64 + c80);
  kreg[1] = *(const ushort8*)(Kb + (size_t)row1 * 64 + c81);
  vreg[0] = *(const ushort8*)(Vb + (size_t)row0 * S_ + c80);
  vreg[1] = *(const ushort8*)(Vb + (size_t)row1 * S_ + c81);

  for (int t0 = 0; t0 < S_; t0 += 64) {
    __syncthreads();
    *(ushort8*)&k_lds[row0][c80] = kreg[0];
    *(ushort8*)&k_lds[row1][c81] = kreg[1];
    *(ushort8*)&v_lds[row0][c80] = vreg[0];
    *(ushort8*)&v_lds[row1][c81] = vreg[1];
    __syncthreads();
    if (t0 + 64 < S_) {
      int t1 = t0 + 64;
      kreg[0] = *(const ushort8*)(Kb + (size_t)(t1 + row0) * 64 + c80);
      kreg[1] = *(const ushort8*)(Kb + (size_t)(t1 + row1) * 64 + c81);
      vreg[0] = *(const ushort8*)(Vb + (size_t)row0 * S_ + t1 + c80);
      vreg[1] = *(const ushort8*)(Vb + (size_t)row1 * S_ + t1 + c81);
    }

    // Transposed scores: St[t][s] = sum_d K[t][d] Q[s][d]
    f32x4 sc[2][4];
    #pragma unroll
    for (int tc = 0; tc < 4; ++tc) {
      bf16x8 kb0 = *(const bf16x8*)&k_lds[tc * 16 + l15][quad * 8];
      bf16x8 kb1 = *(const bf16x8*)&k_lds[tc * 16 + l15][32 + quad * 8];
      #pragma unroll
      for (int g = 0; g < 2; ++g) {
        f32x4 c = {0.f, 0.f, 0.f, 0.f};
        c = __builtin_amdgcn_mfma_f32_16x16x32_bf16(kb0, qa[g][0], c, 0, 0, 0);
        sc[g][tc] = __builtin_amdgcn_mfma_f32_16x16x32_bf16(kb1, qa[g][1], c, 0, 0, 0);
      }
    }

    // exp -> P[s][t] in LDS via contiguous b64 writes
    #pragma unroll
    for (int g = 0; g < 2; ++g)
      #pragma unroll
      for (int tc = 0; tc < 4; ++tc) {
        ushort4_t p4;
        #pragma unroll
        for (int r = 0; r < 4; ++r) p4[r] = f2bf_fast(exp2_raw(sc[g][tc][r]));
        *(ushort4_t*)&p_lds[wave][g][l15][tc * 16 + quad * 4] = p4;
      }

    bf16x8 pa[2][2];
    #pragma unroll
    for (int g = 0; g < 2; ++g) {
      pa[g][0] = *(const bf16x8*)&p_lds[wave][g][l15][quad * 8];
      pa[g][1] = *(const bf16x8*)&p_lds[wave][g][l15][32 + quad * 8];
      l_acc[g] = __builtin_amdgcn_mfma_f32_16x16x32_bf16(pa[g][0], ones, l_acc[g], 0, 0, 0);
      l_acc[g] = __builtin_amdgcn_mfma_f32_16x16x32_bf16(pa[g][1], ones, l_acc[g], 0, 0, 0);
    }
    #pragma unroll
    for (int dc = 0; dc < 4; ++dc) {
      bf16x8 vb0 = *(const bf16x8*)&v_lds[dc * 16 + l15][quad * 8];
      bf16x8 vb1 = *(const bf16x8*)&v_lds[dc * 16 + l15][32 + quad * 8];
      #pragma unroll
      for (int g = 0; g < 2; ++g) {
        o_acc[g][dc] = __builtin_amdgcn_mfma_f32_16x16x32_bf16(pa[g][0], vb0, o_acc[g][dc], 0, 0, 0);
        o_acc[g][dc] = __builtin_amdgcn_mfma_f32_16x16x32_bf16(pa[g][1], vb1, o_acc[g][dc], 0, 0, 0);
      }
    }
  }

  #pragma unroll
  for (int g = 0; g < 2; ++g) {
    float inv_l[4];
    #pragma unroll
    for (int r = 0; r < 4; ++r) inv_l[r] = 1.f / l_acc[g][r];
    #pragma unroll
    for (int dc = 0; dc < 4; ++dc) {
      #pragma unroll
      for (int r = 0; r < 4; ++r) {
        int s = s0w + g * 16 + quad * 4 + r;
        size_t idx = ((size_t)b * S_ + s) * C_ + n * 64 + dc * 16 + l15;
        hflat_bf[idx] = f2bf_fast(o_acc[g][dc][r] * inv_l[r]);
      }
    }
  }
}

// ---------------- Fused INL x3 + proj + residual: h rows resident in LDS ----------------
// 256 blocks (1/CU) x 512 threads (8 waves). Block owns 32 rows of h [32][512] bf16 in LDS.
// W streams from L2 via slab-interleaved layout (1KB contiguous wave loads).
// Explicit 2-deep (4-slab) register pipeline over the flat 64-slab stream (4 steps x 16):
// W loads issue ~32 MFMAs ahead of use, covering L2 latency. launch_bounds(512,2) lifts
// the VGPR cap (was 48 -> compiler issued loads at point-of-use, zero pipelining).
static __device__ __forceinline__ void loadw4(bf16x8* d, const unsigned short* p) {
  d[0] = *(const bf16x8*)(p);
  d[1] = *(const bf16x8*)(p + 512);
  d[2] = *(const bf16x8*)(p + 1024);
  d[3] = *(const bf16x8*)(p + 1536);
}
static __device__ __forceinline__ void cp4(bf16x8* d, const bf16x8* s) {
  d[0] = s[0]; d[1] = s[1]; d[2] = s[2]; d[3] = s[3];
}

__global__ __launch_bounds__(512, 2) void inl_proj_chain(
    const unsigned short* __restrict__ hbf,   // [B*S][512] bf16 (attn out rows)
    const unsigned short* __restrict__ Wi2,   // inl W, slab-interleaved [16][512][32]
    const unsigned short* __restrict__ Wp2,   // proj W, slab-interleaved
    const float* __restrict__ ib, const float* __restrict__ pb,
    const float* __restrict__ x, float* __restrict__ Out) {
  __shared__ __align__(16) unsigned short h_lds[32][520];   // pad 520 breaks 16-way conflicts

  int tid = threadIdx.x;
  int wave = tid >> 6, lane = tid & 63, quad = lane >> 4, l15 = lane & 15;
  int wo = wave * 64;                        // this wave's 64 output channels
  int bid = blockIdx.x;
  int b = bid >> 5, s0 = (bid & 31) * 32;    // 32 blocks per batch image

  // h row loads FIRST so their vmcnt wait doesn't drain the W prefetch queue
  const unsigned short* hsrc = hbf + (size_t)bid * 16384;
  ushort8 hv0 = *(const ushort8*)(hsrc + (size_t)(tid) * 8);
  ushort8 hv1 = *(const ushort8*)(hsrc + (size_t)(512 + tid) * 8);
  ushort8 hv2 = *(const ushort8*)(hsrc + (size_t)(1024 + tid) * 8);
  ushort8 hv3 = *(const ushort8*)(hsrc + (size_t)(1536 + tid) * 8);

  const int wrow = (wo + l15) * 32 + quad * 8;   // per-lane offset inside a W slab

  // W pipeline preload: global slabs 0..3 (all inl W)
  bf16x8 w0[4], w1[4], n0[4], n1[4];
  loadw4(w0, Wi2 + 0 * 16384 + wrow);
  loadw4(w1, Wi2 + 1 * 16384 + wrow);
  loadw4(n0, Wi2 + 2 * 16384 + wrow);
  loadw4(n1, Wi2 + 3 * 16384 + wrow);

  float bias_i[4], bias_p[4];
  #pragma unroll
  for (int j = 0; j < 4; ++j) {
    bias_i[j] = ib[wo + j * 16 + l15];
    bias_p[j] = pb[wo + j * 16 + l15];
  }

  // stage h to LDS (waits only on the 4 h loads)
  *(ushort8*)&h_lds[tid >> 6][(tid & 63) * 8] = hv0;
  { int lin = 512 + tid;  *(ushort8*)&h_lds[lin >> 6][(lin & 63) * 8] = hv1; }
  { int lin = 1024 + tid; *(ushort8*)&h_lds[lin >> 6][(lin & 63) * 8] = hv2; }
  { int lin = 1536 + tid; *(ushort8*)&h_lds[lin >> 6][(lin & 63) * 8] = hv3; }

  f32x4 acc[2][4];
  #pragma unroll
  for (int i = 0; i < 2; ++i)
    #pragma unroll
    for (int j = 0; j < 4; ++j) acc[i][j] = (f32x4){0.f, 0.f, 0.f, 0.f};

  __syncthreads();                           // h_lds ready

  #pragma unroll
  for (int step = 0; step < 4; ++step) {
    #pragma unroll
    for (int sp = 0; sp < 8; ++sp) {
      const int g = step * 16 + sp * 2;      // global slab index of w0
      bf16x8 p0[4], p1[4];
      if (g + 4 < 64) {                      // prefetch 2 slab-pairs ahead (crosses steps)
        loadw4(p0, ((g + 4) < 48 ? Wi2 : Wp2) + ((g + 4) & 15) * 16384 + wrow);
        loadw4(p1, ((g + 5) < 48 ? Wi2 : Wp2) + ((g + 5) & 15) * 16384 + wrow);
      }
      const int sl0 = sp * 2, sl1 = sp * 2 + 1;
      bf16x8 a00 = *(const bf16x8*)&h_lds[l15][sl0 * 32 + quad * 8];
      bf16x8 a10 = *(const bf16x8*)&h_lds[16 + l15][sl0 * 32 + quad * 8];
      bf16x8 a01 = *(const bf16x8*)&h_lds[l15][sl1 * 32 + quad * 8];
      bf16x8 a11 = *(const bf16x8*)&h_lds[16 + l15][sl1 * 32 + quad * 8];
      #pragma unroll
      for (int j = 0; j < 4; ++j) {
        acc[0][j] = __builtin_amdgcn_mfma_f32_16x16x32_bf16(a00, w0[j], acc[0][j], 0, 0, 0);
        acc[1][j] = __builtin_amdgcn_mfma_f32_16x16x32_bf16(a10, w0[j], acc[1][j], 0, 0, 0);
      }
      #pragma unroll
      for (int j = 0; j < 4; ++j) {
        acc[0][j] = __builtin_amdgcn_mfma_f32_16x16x32_bf16(a01, w1[j], acc[0][j], 0, 0, 0);
        acc[1][j] = __builtin_amdgcn_mfma_f32_16x16x32_bf16(a11, w1[j], acc[1][j], 0, 0, 0);
      }
      cp4(w0, n0); cp4(w1, n1);
      if (g + 4 < 64) { cp4(n0, p0); cp4(n1, p1); }
    }
    if (step < 3) {
      __syncthreads();                       // all waves done reading h this step
      #pragma unroll
      for (int i = 0; i < 2; ++i)
        #pragma unroll
        for (int j = 0; j < 4; ++j) {
          int o = wo + j * 16 + l15;
          #pragma unroll
          for (int r = 0; r < 4; ++r) {
            int s = i * 16 + quad * 4 + r;
            float hv = bf2f(h_lds[s][o]);
            h_lds[s][o] = f2bf_fast(hv + DT_STEP * fast_tanh(acc[i][j][r] + bias_i[j]));
            acc[i][j][r] = 0.f;
          }
        }
      __syncthreads();                       // updates visible before next step's reads
    }
  }

  // proj epilogue: Out[b][o][s0..] = x + pb + acc ; 4 consecutive s per reg quad -> f32x4
  #pragma unroll
  for (int i = 0; i < 2; ++i)
    #pragma unroll
    for (int j = 0; j < 4; ++j) {
      int o = wo + j * 16 + l15;
      size_t base = (((size_t)b * 512 + o) << 10) + (size_t)(s0 + i * 16 + quad * 4);
      f32x4 xv = *(const f32x4*)(x + base);
      f32x4 ov;
      #pragma unroll
      for (int r = 0; r < 4; ++r) ov[r] = xv[r] + bias_p[j] + acc[i][j][r];
      *(f32x4*)(Out + base) = ov;
    }
}

extern "C" void kernel_launch(void* const* d_in, const int* in_sizes, int n_in,
                              void* d_out, int out_size, void* d_ws, size_t ws_size,
                              hipStream_t stream) {
  const float* x        = (const float*)d_in[0];
  const float* gn_scale = (const float*)d_in[1];
  const float* gn_bias  = (const float*)d_in[2];
  const float* qkv_w    = (const float*)d_in[3];
  const float* qkv_b    = (const float*)d_in[4];
  const float* proj_w   = (const float*)d_in[5];
  const float* proj_b   = (const float*)d_in[6];
  const float* inl_w    = (const float*)d_in[7];
  const float* inl_b    = (const float*)d_in[8];
  float* out = (float*)d_out;
  float* ws = (float*)d_ws;

  unsigned short* Qt  = (unsigned short*)(ws + 8388608);
  unsigned short* Kt  = (unsigned short*)(ws + 10485760);
  unsigned short* Vt  = (unsigned short*)(ws + 12582912);
  unsigned short* h_t = (unsigned short*)(ws + 14680064);
  unsigned short* Abf = (unsigned short*)(ws + 16777216);
  float* gpart = ws + 18874368;
  unsigned short* qkvw_bf  = (unsigned short*)(ws + 18878464);
  unsigned short* inlw_bf  = qkvw_bf + 786432;
  unsigned short* projw_bf = inlw_bf + 262144;

  prep_kernel<<<1152, 256, 0, stream>>>(qkv_w, inl_w, proj_w, qkvw_bf, inlw_bf, projw_bf, x, gpart);
  gn_apply_t<<<1024, 256, 0, stream>>>(x, gpart, gn_scale, gn_bias, h_t);
  gemm_qkv_mfma<<<dim3(8, 12, 8), 256, 0, stream>>>(qkvw_bf, h_t, qkv_b, Qt, Kt, Vt);
  attn_mfma<<<512, 256, 0, stream>>>(Qt, Kt, Vt, Abf);
  inl_proj_chain<<<256, 512, 0, stream>>>(Abf, inlw_bf, projw_bf, inl_b, proj_b, x, out);
}

// Round 4
// 184.286 us; speedup vs baseline: 1.1147x; 1.0278x over previous
//
#include <hip/hip_runtime.h>
#include <math.h>

#define B_ 8
#define C_ 512
#define S_ 1024
#define HD 64
#define NHEADS 8
#define NGROUPS 8
#define DT_STEP 0.1f
#define EPS_GN 1e-5f
#define LOG2E 1.4426950408889634f

typedef __attribute__((ext_vector_type(8))) short bf16x8;
typedef __attribute__((ext_vector_type(4))) float f32x4;
typedef __attribute__((ext_vector_type(8))) unsigned short ushort8;
typedef __attribute__((ext_vector_type(4))) unsigned short ushort4_t;

static __device__ __forceinline__ unsigned short f2bf(float f) {     // RNE (cold paths)
  unsigned int u = __builtin_bit_cast(unsigned int, f);
  u += 0x7fff + ((u >> 16) & 1);
  return (unsigned short)(u >> 16);
}

static __device__ __forceinline__ unsigned short f2bf_fast(float f) { // round-half-up (hot paths)
  unsigned int u = __builtin_bit_cast(unsigned int, f);
  return (unsigned short)((u + 0x8000u) >> 16);
}

static __device__ __forceinline__ float bf2f(unsigned short u) {
  unsigned int t = ((unsigned int)u) << 16;
  return __builtin_bit_cast(float, t);
}

static __device__ __forceinline__ float exp2_raw(float x) {
  return __builtin_amdgcn_exp2f(x);    // single v_exp_f32
}

static __device__ __forceinline__ float fast_tanh(float x) {
  float xc = fminf(fmaxf(x, -15.f), 15.f);
  float e = exp2_raw(xc * (2.0f * LOG2E));
  return (e - 1.f) / (e + 1.f);
}

// ---------------- prep: cast fp32 weights -> bf16  +  GroupNorm partial sums ----------------
// qkv_w: row-major [o][c] bf16 (consumed by gemm_nt_core LDS staging)
// inl_w / proj_w: SLAB-INTERLEAVED layout W2[(c>>5)*16384 + o*32 + (c&31)]
//   -> each 32-k slab is a contiguous 32KB block [512 o][32 k]; the chain kernel's
//      W-fragment loads (16 o-rows x 64B) become fully-contiguous 1KB wave loads from L2.
__global__ __launch_bounds__(256) void prep_kernel(
    const float* __restrict__ a, const float* __restrict__ b, const float* __restrict__ c,
    unsigned short* __restrict__ A, unsigned short* __restrict__ B, unsigned short* __restrict__ C,
    const float* __restrict__ x, float* __restrict__ gpart) {
  int bid = blockIdx.x;
  int tid = threadIdx.x;
  if (bid < 384) {                     // qkv weights: plain row-major cast
    int off = bid * 2048;
    int i = off + tid * 8;
    f32x4 v0 = *(const f32x4*)(a + i);
    f32x4 v1 = *(const f32x4*)(a + i + 4);
    ushort8 o;
    o[0] = f2bf(v0[0]); o[1] = f2bf(v0[1]); o[2] = f2bf(v0[2]); o[3] = f2bf(v0[3]);
    o[4] = f2bf(v1[0]); o[5] = f2bf(v1[1]); o[6] = f2bf(v1[2]); o[7] = f2bf(v1[3]);
    *(ushort8*)(A + i) = o;
    return;
  }
  if (bid < 640) {                     // inl/proj weights: slab-interleaved cast
    const float* src; unsigned short* dst; int off;
    if (bid < 512) { src = b; dst = B; off = (bid - 384) * 2048; }
    else { src = c; dst = C; off = (bid - 512) * 2048; }
    int i = off + tid * 8;
    f32x4 v0 = *(const f32x4*)(src + i);
    f32x4 v1 = *(const f32x4*)(src + i + 4);
    ushort8 o;
    o[0] = f2bf(v0[0]); o[1] = f2bf(v0[1]); o[2] = f2bf(v0[2]); o[3] = f2bf(v0[3]);
    o[4] = f2bf(v1[0]); o[5] = f2bf(v1[1]); o[6] = f2bf(v1[2]); o[7] = f2bf(v1[3]);
    int orow = i >> 9, cbase = i & 511;
    int dsti = (cbase >> 5) * 16384 + orow * 32 + (cbase & 31);
    *(ushort8*)(dst + dsti) = o;
    return;
  }
  int sbid = bid - 640;
  int bg = sbid >> 3, chunk = sbid & 7;
  const float* xp = x + (size_t)bg * 65536 + (size_t)chunk * 8192;
  float sum = 0.f, sq = 0.f;
  #pragma unroll
  for (int i = 0; i < 8; ++i) {
    f32x4 v = *(const f32x4*)(xp + i * 1024 + tid * 4);
    sum += v[0] + v[1] + v[2] + v[3];
    sq += v[0]*v[0] + v[1]*v[1] + v[2]*v[2] + v[3]*v[3];
  }
  #pragma unroll
  for (int off = 32; off >= 1; off >>= 1) {
    sum += __shfl_xor(sum, off, 64);
    sq  += __shfl_xor(sq, off, 64);
  }
  __shared__ float s1[4], s2[4];
  int wave = tid >> 6, lane = tid & 63;
  if (lane == 0) { s1[wave] = sum; s2[wave] = sq; }
  __syncthreads();
  if (tid == 0) {
    float S = s1[0] + s1[1] + s1[2] + s1[3];
    float Q = s2[0] + s2[1] + s2[2] + s2[3];
    gpart[bg * 16 + chunk * 2] = S;
    gpart[bg * 16 + chunk * 2 + 1] = Q;
  }
}

// ---------------- GroupNorm pass 2: normalize + transpose to h_t[B,S,C] bf16 ----------------
__global__ __launch_bounds__(256) void gn_apply_t(
    const float* __restrict__ x, const float* __restrict__ gpart,
    const float* __restrict__ scale, const float* __restrict__ bias,
    unsigned short* __restrict__ h_t) {
  int bid = blockIdx.x;
  int bg = bid >> 4, st = bid & 15;
  int b = bg >> 3, g = bg & 7;
  float S = 0.f, Q = 0.f;
  #pragma unroll
  for (int i = 0; i < 8; ++i) {
    S += gpart[bg * 16 + i * 2];
    Q += gpart[bg * 16 + i * 2 + 1];
  }
  float mean = S / 65536.f;
  float var = Q / 65536.f - mean * mean;
  float inv = rsqrtf(var + EPS_GN);

  int tid = threadIdx.x;
  int sl = tid >> 2;
  int cq = (tid & 3) * 16;
  float sA[16], sB[16];
  #pragma unroll
  for (int u = 0; u < 16; ++u) {
    float scv = scale[g * 64 + cq + u];
    sA[u] = inv * scv;
    sB[u] = bias[g * 64 + cq + u] - mean * inv * scv;
  }

  const float* xp = x + ((size_t)b * C_ + (size_t)g * 64) * S_;
  __shared__ float tile[64][65];
  #pragma unroll
  for (int it = 0; it < 16; ++it) {
    int lin = it * 256 + tid;
    int c = lin >> 6, s = lin & 63;
    tile[c][s] = xp[(size_t)c * S_ + st * 64 + s];
  }
  __syncthreads();
  unsigned short vals[16];
  #pragma unroll
  for (int u = 0; u < 16; ++u)
    vals[u] = f2bf_fast(tile[cq + u][sl] * sA[u] + sB[u]);
  unsigned short* dst = h_t + ((size_t)b * S_ + st * 64 + sl) * C_ + g * 64 + cq;
  ushort8 lo, hi;
  #pragma unroll
  for (int u = 0; u < 8; ++u) { lo[u] = vals[u]; hi[u] = vals[u + 8]; }
  *(ushort8*)dst = lo;
  *(ushort8*)(dst + 8) = hi;
}

// ---------------- NT GEMM core, register-prefetch pipelined staging ----------------
// C[MB,NB] = A[MB,512] * B[NB,512]^T ; next k-slab loads issue during MFMA phase.
template<int MB, int NB, int WMG, int WNG>
__device__ __forceinline__ void gemm_nt_core(
    const unsigned short* __restrict__ Ab,
    const unsigned short* __restrict__ Bb,
    unsigned short* ldsA, unsigned short* ldsB,
    f32x4* acc) {
  constexpr int TI = (MB / WMG) / 16;
  constexpr int TJ = (NB / WNG) / 16;
  constexpr int NQA = MB * 4 / 256;          // 16B chunks per thread (A)
  constexpr int NQB = NB * 4 / 256;
  const int K = 512;
  const int tid = threadIdx.x;
  const int w = tid >> 6, lane = tid & 63, quad = lane >> 4, l15 = lane & 15;
  const int wm = (WNG == 1) ? w : ((WMG == 1) ? 0 : (w >> 1));
  const int wn = (WNG == 1) ? 0 : ((WMG == 1) ? w : (w & 1));

  ushort8 apf[NQA], bpf[NQB];
  #pragma unroll
  for (int q = 0; q < NQA; ++q) {
    int c = q * 256 + tid;
    apf[q] = *(const ushort8*)(Ab + (size_t)(c >> 2) * K + (c & 3) * 8);
  }
  #pragma unroll
  for (int q = 0; q < NQB; ++q) {
    int c = q * 256 + tid;
    bpf[q] = *(const ushort8*)(Bb + (size_t)(c >> 2) * K + (c & 3) * 8);
  }

  for (int k0 = 0; k0 < K; k0 += 32) {
    __syncthreads();                         // prior slab consumed
    #pragma unroll
    for (int q = 0; q < NQA; ++q) {
      int c = q * 256 + tid;
      *(ushort8*)(ldsA + c * 8) = apf[q];
    }
    #pragma unroll
    for (int q = 0; q < NQB; ++q) {
      int c = q * 256 + tid;
      *(ushort8*)(ldsB + c * 8) = bpf[q];
    }
    __syncthreads();
    if (k0 + 32 < K) {                       // issue next-slab loads; waited next iter
      #pragma unroll
      for (int q = 0; q < NQA; ++q) {
        int c = q * 256 + tid;
        apf[q] = *(const ushort8*)(Ab + (size_t)(c >> 2) * K + k0 + 32 + (c & 3) * 8);
      }
      #pragma unroll
      for (int q = 0; q < NQB; ++q) {
        int c = q * 256 + tid;
        bpf[q] = *(const ushort8*)(Bb + (size_t)(c >> 2) * K + k0 + 32 + (c & 3) * 8);
      }
    }
    bf16x8 af[TI], bfr[TJ];
    #pragma unroll
    for (int i = 0; i < TI; ++i)
      af[i] = *(const bf16x8*)(ldsA + (wm * (MB / WMG) + i * 16 + l15) * 32 + quad * 8);
    #pragma unroll
    for (int j = 0; j < TJ; ++j)
      bfr[j] = *(const bf16x8*)(ldsB + (wn * (NB / WNG) + j * 16 + l15) * 32 + quad * 8);
    #pragma unroll
    for (int i = 0; i < TI; ++i)
      #pragma unroll
      for (int j = 0; j < TJ; ++j)
        acc[i * TJ + j] = __builtin_amdgcn_mfma_f32_16x16x32_bf16(af[i], bfr[j], acc[i * TJ + j], 0, 0, 0);
  }
}

// ---------------- QKV GEMM: W_bf[1536,512] x h_t[b][1024,512]^T ----------------
__global__ __launch_bounds__(256) void gemm_qkv_mfma(
    const unsigned short* __restrict__ Wbf, const unsigned short* __restrict__ h_t,
    const float* __restrict__ bias,
    unsigned short* __restrict__ Qt, unsigned short* __restrict__ Kt,
    unsigned short* __restrict__ Vt) {
  __shared__ __align__(16) unsigned short ldsA[128 * 32];
  __shared__ __align__(16) unsigned short ldsB[128 * 32];
  int b = blockIdx.z;
  int bm = blockIdx.y * 128, bn = blockIdx.x * 128;
  f32x4 acc[16];
  #pragma unroll
  for (int t = 0; t < 16; ++t) acc[t] = (f32x4){0.f, 0.f, 0.f, 0.f};
  gemm_nt_core<128, 128, 2, 2>(Wbf + (size_t)bm * 512,
                               h_t + ((size_t)b * S_ + bn) * 512, ldsA, ldsB, acc);
  int tid = threadIdx.x, w = tid >> 6, lane = tid & 63, quad = lane >> 4, l15 = lane & 15;
  int wm = w >> 1, wn = w & 1;
  int tensor = bm >> 9;
  float qscale = (tensor == 0) ? 0.125f * LOG2E : 1.0f;
  #pragma unroll
  for (int i = 0; i < 4; ++i) {
    #pragma unroll
    for (int j = 0; j < 4; ++j) {
      int m0 = bm + wm * 64 + i * 16 + quad * 4;
      int ng = bn + wn * 64 + j * 16 + l15;
      f32x4 v = acc[i * 4 + j];
      if (tensor < 2) {
        int head = (m0 >> 6) & 7, d0 = m0 & 63;
        ushort4_t pk;
        #pragma unroll
        for (int r = 0; r < 4; ++r) pk[r] = f2bf((v[r] + bias[m0 + r]) * qscale);
        unsigned short* dst = (tensor ? Kt : Qt) +
            (((size_t)(b * 8 + head) * S_ + ng) * 64 + d0);
        *(ushort4_t*)dst = pk;
      } else {
        #pragma unroll
        for (int r = 0; r < 4; ++r)
          Vt[(size_t)b * (C_ * S_) + (size_t)(m0 - 1024 + r) * S_ + ng] = f2bf(v[r] + bias[m0 + r]);
      }
    }
  }
}

// ---------------- Flash attention: transposed scores, 2 q-groups/wave, reg-prefetched K/V ----------------
// grid 512: bid = sblk*64 + (b*8+n); 4 waves x 32 q-rows (2 groups of 16)
__global__ __launch_bounds__(256) void attn_mfma(
    const unsigned short* __restrict__ Qt,   // [B][NH][S][HD] (pre-scaled, incl log2e)
    const unsigned short* __restrict__ Kt,
    const unsigned short* __restrict__ Vt,   // [B][C][S]
    unsigned short* __restrict__ hflat_bf) { // [B][S][C] bf16
  int tid = threadIdx.x, wave = tid >> 6, lane = tid & 63;
  int quad = lane >> 4, l15 = lane & 15;
  int bid = blockIdx.x;
  int bn = bid & 63, sblk = bid >> 6, b = bn >> 3, n = bn & 7;
  int s0w = sblk * 128 + wave * 32;

  __shared__ unsigned short k_lds[64][72];
  __shared__ unsigned short v_lds[64][72];
  __shared__ unsigned short p_lds[4][2][16][72];  // [wave][group][s][t], A-layout

  const unsigned short* Kb = Kt + ((size_t)(b * 8 + n)) * S_ * 64;
  const unsigned short* Vb = Vt + ((size_t)b * C_ + n * 64) * S_;

  bf16x8 qa[2][2];
  #pragma unroll
  for (int g = 0; g < 2; ++g) {
    const unsigned short* Qb = Qt + (((size_t)(b * 8 + n)) * S_ + s0w + g * 16 + l15) * 64;
    qa[g][0] = *(const bf16x8*)(Qb + quad * 8);
    qa[g][1] = *(const bf16x8*)(Qb + 32 + quad * 8);
  }

  bf16x8 ones;
  #pragma unroll
  for (int j = 0; j < 8; ++j) ones[j] = (short)0x3F80;

  f32x4 o_acc[2][4];
  f32x4 l_acc[2];
  #pragma unroll
  for (int g = 0; g < 2; ++g) {
    l_acc[g] = (f32x4){0.f, 0.f, 0.f, 0.f};
    #pragma unroll
    for (int dc = 0; dc < 4; ++dc) o_acc[g][dc] = (f32x4){0.f, 0.f, 0.f, 0.f};
  }

  int row0 = tid >> 3, c80 = (tid & 7) * 8;
  int row1 = (tid + 256) >> 3, c81 = c80;

  ushort8 kreg[2], vreg[2];
  kreg[0] = *(const ushort8*)(Kb + (size_t)row0 * 64 + c80);
  kreg[1] = *(const ushort8*)(Kb + (size_t)row1 * 64 + c81);
  vreg[0] = *(const ushort8*)(Vb + (size_t)row0 * S_ + c80);
  vreg[1] = *(const ushort8*)(Vb + (size_t)row1 * S_ + c81);

  for (int t0 = 0; t0 < S_; t0 += 64) {
    __syncthreads();
    *(ushort8*)&k_lds[row0][c80] = kreg[0];
    *(ushort8*)&k_lds[row1][c81] = kreg[1];
    *(ushort8*)&v_lds[row0][c80] = vreg[0];
    *(ushort8*)&v_lds[row1][c81] = vreg[1];
    __syncthreads();
    if (t0 + 64 < S_) {
      int t1 = t0 + 64;
      kreg[0] = *(const ushort8*)(Kb + (size_t)(t1 + row0) * 64 + c80);
      kreg[1] = *(const ushort8*)(Kb + (size_t)(t1 + row1) * 64 + c81);
      vreg[0] = *(const ushort8*)(Vb + (size_t)row0 * S_ + t1 + c80);
      vreg[1] = *(const ushort8*)(Vb + (size_t)row1 * S_ + t1 + c81);
    }

    // Transposed scores: St[t][s] = sum_d K[t][d] Q[s][d]
    f32x4 sc[2][4];
    #pragma unroll
    for (int tc = 0; tc < 4; ++tc) {
      bf16x8 kb0 = *(const bf16x8*)&k_lds[tc * 16 + l15][quad * 8];
      bf16x8 kb1 = *(const bf16x8*)&k_lds[tc * 16 + l15][32 + quad * 8];
      #pragma unroll
      for (int g = 0; g < 2; ++g) {
        f32x4 c = {0.f, 0.f, 0.f, 0.f};
        c = __builtin_amdgcn_mfma_f32_16x16x32_bf16(kb0, qa[g][0], c, 0, 0, 0);
        sc[g][tc] = __builtin_amdgcn_mfma_f32_16x16x32_bf16(kb1, qa[g][1], c, 0, 0, 0);
      }
    }

    // exp -> P[s][t] in LDS via contiguous b64 writes
    #pragma unroll
    for (int g = 0; g < 2; ++g)
      #pragma unroll
      for (int tc = 0; tc < 4; ++tc) {
        ushort4_t p4;
        #pragma unroll
        for (int r = 0; r < 4; ++r) p4[r] = f2bf_fast(exp2_raw(sc[g][tc][r]));
        *(ushort4_t*)&p_lds[wave][g][l15][tc * 16 + quad * 4] = p4;
      }

    bf16x8 pa[2][2];
    #pragma unroll
    for (int g = 0; g < 2; ++g) {
      pa[g][0] = *(const bf16x8*)&p_lds[wave][g][l15][quad * 8];
      pa[g][1] = *(const bf16x8*)&p_lds[wave][g][l15][32 + quad * 8];
      l_acc[g] = __builtin_amdgcn_mfma_f32_16x16x32_bf16(pa[g][0], ones, l_acc[g], 0, 0, 0);
      l_acc[g] = __builtin_amdgcn_mfma_f32_16x16x32_bf16(pa[g][1], ones, l_acc[g], 0, 0, 0);
    }
    #pragma unroll
    for (int dc = 0; dc < 4; ++dc) {
      bf16x8 vb0 = *(const bf16x8*)&v_lds[dc * 16 + l15][quad * 8];
      bf16x8 vb1 = *(const bf16x8*)&v_lds[dc * 16 + l15][32 + quad * 8];
      #pragma unroll
      for (int g = 0; g < 2; ++g) {
        o_acc[g][dc] = __builtin_amdgcn_mfma_f32_16x16x32_bf16(pa[g][0], vb0, o_acc[g][dc], 0, 0, 0);
        o_acc[g][dc] = __builtin_amdgcn_mfma_f32_16x16x32_bf16(pa[g][1], vb1, o_acc[g][dc], 0, 0, 0);
      }
    }
  }

  #pragma unroll
  for (int g = 0; g < 2; ++g) {
    float inv_l[4];
    #pragma unroll
    for (int r = 0; r < 4; ++r) inv_l[r] = 1.f / l_acc[g][r];
    #pragma unroll
    for (int dc = 0; dc < 4; ++dc) {
      #pragma unroll
      for (int r = 0; r < 4; ++r) {
        int s = s0w + g * 16 + quad * 4 + r;
        size_t idx = ((size_t)b * S_ + s) * C_ + n * 64 + dc * 16 + l15;
        hflat_bf[idx] = f2bf_fast(o_acc[g][dc][r] * inv_l[r]);
      }
    }
  }
}

// ---------------- Fused INL x3 + proj + residual: h rows resident in LDS ----------------
// 256 blocks x 1024 threads (16 waves = 4/SIMD). Block owns 32 rows of h in LDS.
// W streams from L2 (slab-interleaved layout -> 1KB contiguous wave loads).
// Copy-free static 4-deep register ring over the flat 64-slab stream: each slab's
// consume is followed by a prefetch of slab+4 into the SAME registers (WAR free:
// MFMA reads operands at issue). 8 loads in flight/wave; no per-iter vmcnt drain.
__global__ __launch_bounds__(1024, 4) void inl_proj_chain(
    const unsigned short* __restrict__ hbf,   // [B*S][512] bf16 (attn out rows)
    const unsigned short* __restrict__ Wi2,   // inl W, slab-interleaved [16][512][32]
    const unsigned short* __restrict__ Wp2,   // proj W, slab-interleaved
    const float* __restrict__ ib, const float* __restrict__ pb,
    const float* __restrict__ x, float* __restrict__ Out) {
  __shared__ __align__(16) unsigned short h_lds[32][520];   // pad 520 breaks stride conflicts

  int tid = threadIdx.x;
  int wave = tid >> 6, lane = tid & 63, quad = lane >> 4, l15 = lane & 15;
  int wo = wave * 32;                        // this wave's 32 output channels
  int bid = blockIdx.x;
  int b = bid >> 5, s0 = (bid & 31) * 32;    // 32 blocks per batch image

  // h row loads FIRST so their vmcnt wait doesn't stall the W prefetch stream
  const unsigned short* hsrc = hbf + (size_t)bid * 16384;
  ushort8 hv0 = *(const ushort8*)(hsrc + (size_t)tid * 8);
  ushort8 hv1 = *(const ushort8*)(hsrc + (size_t)(1024 + tid) * 8);

  const int wrow = (wo + l15) * 32 + quad * 8;   // per-lane offset inside a W slab

#define PREF_(na, nb, s) { \
    const unsigned short* wp_ = (((s) < 48) ? Wi2 : Wp2) + ((s) & 15) * 16384 + wrow; \
    na = *(const bf16x8*)(wp_); \
    nb = *(const bf16x8*)(wp_ + 512); }

  bf16x8 q0a, q0b, q1a, q1b, q2a, q2b, q3a, q3b;
  PREF_(q0a, q0b, 0); PREF_(q1a, q1b, 1); PREF_(q2a, q2b, 2); PREF_(q3a, q3b, 3);

  float bi0 = ib[wo + l15], bi1 = ib[wo + 16 + l15];
  float bp0 = pb[wo + l15], bp1 = pb[wo + 16 + l15];

  // stage h to LDS (waits only on the 2 h loads)
  *(ushort8*)&h_lds[tid >> 6][(tid & 63) * 8] = hv0;
  { int lin = 1024 + tid; *(ushort8*)&h_lds[lin >> 6][(lin & 63) * 8] = hv1; }

  f32x4 acc00 = {0.f,0.f,0.f,0.f}, acc01 = {0.f,0.f,0.f,0.f};
  f32x4 acc10 = {0.f,0.f,0.f,0.f}, acc11 = {0.f,0.f,0.f,0.f};

  __syncthreads();                           // h_lds ready

#define DOSLAB_(na, nb, s) { \
    bf16x8 a0_ = *(const bf16x8*)&h_lds[l15][((s) & 15) * 32 + quad * 8]; \
    bf16x8 a1_ = *(const bf16x8*)&h_lds[16 + l15][((s) & 15) * 32 + quad * 8]; \
    acc00 = __builtin_amdgcn_mfma_f32_16x16x32_bf16(a0_, na, acc00, 0, 0, 0); \
    acc10 = __builtin_amdgcn_mfma_f32_16x16x32_bf16(a1_, na, acc10, 0, 0, 0); \
    acc01 = __builtin_amdgcn_mfma_f32_16x16x32_bf16(a0_, nb, acc01, 0, 0, 0); \
    acc11 = __builtin_amdgcn_mfma_f32_16x16x32_bf16(a1_, nb, acc11, 0, 0, 0); }

#define STEP4_(s) \
    DOSLAB_(q0a, q0b, (s));     if ((s) + 4 < 64) PREF_(q0a, q0b, (s) + 4); \
    DOSLAB_(q1a, q1b, (s) + 1); if ((s) + 5 < 64) PREF_(q1a, q1b, (s) + 5); \
    DOSLAB_(q2a, q2b, (s) + 2); if ((s) + 6 < 64) PREF_(q2a, q2b, (s) + 6); \
    DOSLAB_(q3a, q3b, (s) + 3); if ((s) + 7 < 64) PREF_(q3a, q3b, (s) + 7);

#define UPDATE_ { \
    __syncthreads(); \
    _Pragma("unroll") \
    for (int r = 0; r < 4; ++r) { \
      int sa = quad * 4 + r, sb = 16 + quad * 4 + r; \
      int o0 = wo + l15, o1 = wo + 16 + l15; \
      h_lds[sa][o0] = f2bf_fast(bf2f(h_lds[sa][o0]) + DT_STEP * fast_tanh(acc00[r] + bi0)); \
      h_lds[sa][o1] = f2bf_fast(bf2f(h_lds[sa][o1]) + DT_STEP * fast_tanh(acc01[r] + bi1)); \
      h_lds[sb][o0] = f2bf_fast(bf2f(h_lds[sb][o0]) + DT_STEP * fast_tanh(acc10[r] + bi0)); \
      h_lds[sb][o1] = f2bf_fast(bf2f(h_lds[sb][o1]) + DT_STEP * fast_tanh(acc11[r] + bi1)); \
    } \
    acc00 = (f32x4){0.f,0.f,0.f,0.f}; acc01 = (f32x4){0.f,0.f,0.f,0.f}; \
    acc10 = (f32x4){0.f,0.f,0.f,0.f}; acc11 = (f32x4){0.f,0.f,0.f,0.f}; \
    __syncthreads(); }

  STEP4_(0); STEP4_(4); STEP4_(8); STEP4_(12);
  UPDATE_;                                   // prefetched slabs 16-19 stay in flight
  STEP4_(16); STEP4_(20); STEP4_(24); STEP4_(28);
  UPDATE_;
  STEP4_(32); STEP4_(36); STEP4_(40); STEP4_(44);
  UPDATE_;
  STEP4_(48); STEP4_(52); STEP4_(56); STEP4_(60);

  // proj epilogue: Out[b][o][s0..] = x + pb + acc ; 4 consecutive s per reg quad -> f32x4
  {
    int o0 = wo + l15, o1 = wo + 16 + l15;
    size_t base0 = (((size_t)b * 512 + o0) << 10) + (size_t)(s0 + quad * 4);
    size_t base1 = (((size_t)b * 512 + o1) << 10) + (size_t)(s0 + quad * 4);
    f32x4 xv, ov;
    xv = *(const f32x4*)(x + base0);
    #pragma unroll
    for (int r = 0; r < 4; ++r) ov[r] = xv[r] + bp0 + acc00[r];
    *(f32x4*)(Out + base0) = ov;
    xv = *(const f32x4*)(x + base0 + 16);
    #pragma unroll
    for (int r = 0; r < 4; ++r) ov[r] = xv[r] + bp0 + acc10[r];
    *(f32x4*)(Out + base0 + 16) = ov;
    xv = *(const f32x4*)(x + base1);
    #pragma unroll
    for (int r = 0; r < 4; ++r) ov[r] = xv[r] + bp1 + acc01[r];
    *(f32x4*)(Out + base1) = ov;
    xv = *(const f32x4*)(x + base1 + 16);
    #pragma unroll
    for (int r = 0; r < 4; ++r) ov[r] = xv[r] + bp1 + acc11[r];
    *(f32x4*)(Out + base1 + 16) = ov;
  }
#undef PREF_
#undef DOSLAB_
#undef STEP4_
#undef UPDATE_
}

extern "C" void kernel_launch(void* const* d_in, const int* in_sizes, int n_in,
                              void* d_out, int out_size, void* d_ws, size_t ws_size,
                              hipStream_t stream) {
  const float* x        = (const float*)d_in[0];
  const float* gn_scale = (const float*)d_in[1];
  const float* gn_bias  = (const float*)d_in[2];
  const float* qkv_w    = (const float*)d_in[3];
  const float* qkv_b    = (const float*)d_in[4];
  const float* proj_w   = (const float*)d_in[5];
  const float* proj_b   = (const float*)d_in[6];
  const float* inl_w    = (const float*)d_in[7];
  const float* inl_b    = (const float*)d_in[8];
  float* out = (float*)d_out;
  float* ws = (float*)d_ws;

  unsigned short* Qt  = (unsigned short*)(ws + 8388608);
  unsigned short* Kt  = (unsigned short*)(ws + 10485760);
  unsigned short* Vt  = (unsigned short*)(ws + 12582912);
  unsigned short* h_t = (unsigned short*)(ws + 14680064);
  unsigned short* Abf = (unsigned short*)(ws + 16777216);
  float* gpart = ws + 18874368;
  unsigned short* qkvw_bf  = (unsigned short*)(ws + 18878464);
  unsigned short* inlw_bf  = qkvw_bf + 786432;
  unsigned short* projw_bf = inlw_bf + 262144;

  prep_kernel<<<1152, 256, 0, stream>>>(qkv_w, inl_w, proj_w, qkvw_bf, inlw_bf, projw_bf, x, gpart);
  gn_apply_t<<<1024, 256, 0, stream>>>(x, gpart, gn_scale, gn_bias, h_t);
  gemm_qkv_mfma<<<dim3(8, 12, 8), 256, 0, stream>>>(qkvw_bf, h_t, qkv_b, Qt, Kt, Vt);
  attn_mfma<<<512, 256, 0, stream>>>(Qt, Kt, Vt, Abf);
  inl_proj_chain<<<256, 1024, 0, stream>>>(Abf, inlw_bf, projw_bf, inl_b, proj_b, x, out);
}